// Round 10
// baseline (63.816 us; speedup 1.0000x reference)
//
#include <hip/hip_runtime.h>

#define B_   4
#define LQ_  256
#define LK_  512
#define DIN_ 512
#define H_   256
#define DV_  512

#define L2E 1.4426950408889634f   // log2(e)
// tanh(x) = 1 - 2/(e^{2x}+1);  e^{2(q+k)} = (e^q * e^k)^2.
// combine stores eq = 2^clamp(qp*L2E,±126) (finite, nonzero -> no NaN).

// =====================================================================
// Kernel A: proj PARTIAL GEMM. tile 64 rows x 128 h x 128 d (d-split 4).
// 256 thr: hthr=t&31 (h=4*hthr), rthr=t>>5 (rows rthr*8..+7). micro 8rx4h.
// LDS: xs 17.4KB + ws 33.8KB = 51KB. 24 b128 LDS reads / 256 FMA = 1.5B/FMA.
// grid = Q:16rt*2ht*4ds=128  +  K:32rt*2ht*4ds=256  -> 384 blocks (~272 live).
// Q out: qpart[ds][(b,i)][h] row-major. K out: ekTpart[ds][b][h][j] transposed.
// =====================================================================
__global__ __launch_bounds__(256) void proj_partial_kernel(
    const float* __restrict__ Q, const float* __restrict__ K,
    const float* __restrict__ Wq, const float* __restrict__ Wk,
    const int* __restrict__ valid_lens,
    float* __restrict__ qpart, float* __restrict__ ekTpart) {
  __shared__ float xs[64][68];
  __shared__ float ws[64][132];

  const int blk = blockIdx.x;
  const bool isQ = blk < 128;
  int b, row0, h0, ds;
  if (isQ) {
    const int qi = blk;
    ds = qi & 3; h0 = ((qi >> 2) & 1) * 128;
    const int rt = qi >> 3;            // 0..15
    b = rt >> 2; row0 = (rt & 3) * 64;
  } else {
    const int u = blk - 128;
    ds = u & 3; h0 = ((u >> 2) & 1) * 128;
    const int rt = u >> 3;             // 0..31, batch-interleaved
    b = rt & 3; row0 = (rt >> 2) * 64;
    if (row0 >= valid_lens[b]) return; // dead K tile (uniform, before barriers)
  }
  const int L = isQ ? LQ_ : LK_;
  const float* __restrict__ X = (isQ ? Q : K) + ((size_t)(b * L + row0)) * DIN_ + ds * 128;
  const float* __restrict__ Wb = (isQ ? Wq : Wk) + (size_t)(ds * 128) * H_ + h0;

  const int t = threadIdx.x;
  const int hthr = t & 31;    // h = h0 + 4*hthr
  const int rthr = t >> 5;    // rows row0 + rthr*8 .. +7

  float acc[8][4];
#pragma unroll
  for (int r = 0; r < 8; ++r)
#pragma unroll
    for (int c = 0; c < 4; ++c) acc[r][c] = 0.f;

  for (int dd = 0; dd < 128; dd += 64) {
    __syncthreads();
    // stage X tile 64r x 64d: 1024 f4 / 256 thr = 4 each
#pragma unroll
    for (int u = 0; u < 4; ++u) {
      const int f = t + 256 * u;
      const int r = f >> 4, c4 = (f & 15) << 2;
      *(float4*)&xs[r][c4] = *(const float4*)&X[(size_t)r * DIN_ + dd + c4];
    }
    // stage W tile 64d x 128h: 2048 f4 / 256 thr = 8 each
#pragma unroll
    for (int u = 0; u < 8; ++u) {
      const int f = t + 256 * u;
      const int k = f >> 5, c4 = (f & 31) << 2;
      *(float4*)&ws[k][c4] = *(const float4*)&Wb[(size_t)(dd + k) * H_ + c4];
    }
    __syncthreads();

    for (int k = 0; k < 64; k += 8) {
      float4 w4[8];
#pragma unroll
      for (int k8 = 0; k8 < 8; ++k8)
        w4[k8] = *(const float4*)&ws[k + k8][4 * hthr];
#pragma unroll
      for (int rr = 0; rr < 8; ++rr) {
        const float4 xa = *(const float4*)&xs[rthr * 8 + rr][k];
        const float4 xb = *(const float4*)&xs[rthr * 8 + rr][k + 4];
        const float xv[8] = {xa.x, xa.y, xa.z, xa.w, xb.x, xb.y, xb.z, xb.w};
#pragma unroll
        for (int k8 = 0; k8 < 8; ++k8) {
          acc[rr][0] = fmaf(xv[k8], w4[k8].x, acc[rr][0]);
          acc[rr][1] = fmaf(xv[k8], w4[k8].y, acc[rr][1]);
          acc[rr][2] = fmaf(xv[k8], w4[k8].z, acc[rr][2]);
          acc[rr][3] = fmaf(xv[k8], w4[k8].w, acc[rr][3]);
        }
      }
    }
  }

  if (isQ) {
    // qpart[ds][(b,i)][h] row-major
    float* dst = qpart + (size_t)ds * (B_ * LQ_ * H_);
#pragma unroll
    for (int rr = 0; rr < 8; ++rr) {
      const int row = row0 + rthr * 8 + rr;
      float4 o = {acc[rr][0], acc[rr][1], acc[rr][2], acc[rr][3]};
      *(float4*)&dst[(size_t)(b * LQ_ + row) * H_ + h0 + 4 * hthr] = o;
    }
  } else {
    // ekTpart[ds][b][h][j] transposed
    float* dst = ekTpart + (size_t)ds * (B_ * H_ * LK_);
#pragma unroll
    for (int c = 0; c < 4; ++c) {
      const int h = h0 + 4 * hthr + c;
      float* p = &dst[((size_t)b * H_ + h) * LK_ + row0 + rthr * 8];
      float4 lo = {acc[0][c], acc[1][c], acc[2][c], acc[3][c]};
      float4 hi = {acc[4][c], acc[5][c], acc[6][c], acc[7][c]};
      *(float4*)p = lo;
      *(float4*)(p + 4) = hi;
    }
  }
}

// =====================================================================
// Kernel B: combine 4 d-partials + exp convert. Pure elementwise f4.
// q: 65536 f4 -> eq[b][i][h];  k: 131072 f4 -> ekT[b][h][j].
// block 0 also computes wsum. grid 384 x 512 (exact).
// =====================================================================
__global__ __launch_bounds__(512) void combine_exp_kernel(
    const float* __restrict__ qpart, const float* __restrict__ ekTpart,
    const float* __restrict__ wv,
    float* __restrict__ eq, float* __restrict__ ekT, float* __restrict__ wsum) {
  const int idx = blockIdx.x * 512 + threadIdx.x;
  const int NQ4 = B_ * LQ_ * H_ / 4;     // 65536
  const float4* src;
  float4* dst;
  size_t stride4;
  int k4;
  if (idx < NQ4) {
    src = (const float4*)qpart; dst = (float4*)eq;
    stride4 = NQ4; k4 = idx;
  } else {
    src = (const float4*)ekTpart; dst = (float4*)ekT;
    stride4 = B_ * H_ * LK_ / 4; k4 = idx - NQ4;
  }
  float4 a = src[k4];
  float4 b1 = src[stride4 + k4];
  float4 c = src[2 * stride4 + k4];
  float4 d = src[3 * stride4 + k4];
  float4 o;
  o.x = exp2f(fminf(fmaxf((a.x + b1.x + c.x + d.x) * L2E, -126.f), 126.f));
  o.y = exp2f(fminf(fmaxf((a.y + b1.y + c.y + d.y) * L2E, -126.f), 126.f));
  o.z = exp2f(fminf(fmaxf((a.z + b1.z + c.z + d.z) * L2E, -126.f), 126.f));
  o.w = exp2f(fminf(fmaxf((a.w + b1.w + c.w + d.w) * L2E, -126.f), 126.f));
  dst[k4] = o;

  if (blockIdx.x == 0 && threadIdx.x < 64) {
    const int t = threadIdx.x;
    float s = wv[t] + wv[t + 64] + wv[t + 128] + wv[t + 192];
#pragma unroll
    for (int off = 32; off; off >>= 1) s += __shfl_xor(s, off);
    if (t == 0) *wsum = s;
  }
}

// =====================================================================
// Kernel C: sc[(b,i)][j] = Wsum - 2*sum_h wv[h]*rcp((eq*ek)^2+1)
// thread = j (ekT coalesced, 1B global/element); eq & wv via SCALAR loads
// (wave-uniform -> broadcast free). TI=4 i per thread amortizes ekT x4.
// grid = B * (LQ/4) * 2 jc = 512 blocks x 256 thr; block/wave mask on j.
// =====================================================================
__global__ __launch_bounds__(256) void scores_kernel(
    const float* __restrict__ eq, const float* __restrict__ ekT,
    const float* __restrict__ wv, const float* __restrict__ wsum,
    const int* __restrict__ valid_lens, float* __restrict__ sc) {
  const int blk = blockIdx.x;
  const int b  = blk & 3;
  const int i0 = ((blk >> 2) & 63) * 4;
  const int jc = blk >> 8;
  const int vl = valid_lens[b];
  if (jc * 256 >= vl) return;                       // whole block masked
  const int t = threadIdx.x;
  if (jc * 256 + ((t >> 6) << 6) >= vl) return;     // wave-uniform skip
  const int j = jc * 256 + t;

  const float* __restrict__ kcol = ekT + (size_t)b * H_ * LK_ + j;
  const float* __restrict__ q0 = eq + (size_t)(b * LQ_ + i0) * H_;  // uniform
  const float Wsum = *wsum;

  float a0 = 0.f, a1 = 0.f, a2 = 0.f, a3 = 0.f;
  for (int h = 0; h < H_; h += 8) {
    float kv[8];
#pragma unroll
    for (int u = 0; u < 8; ++u) kv[u] = kcol[(size_t)(h + u) * LK_];  // coalesced
    const float4 wa = *(const float4*)&wv[h];       // uniform
    const float4 wb = *(const float4*)&wv[h + 4];
    const float ww[8] = {wa.x, wa.y, wa.z, wa.w, wb.x, wb.y, wb.z, wb.w};
#pragma unroll
    for (int ii = 0; ii < 4; ++ii) {
      const float4 qa = *(const float4*)&q0[ii * H_ + h];      // uniform s_load
      const float4 qb = *(const float4*)&q0[ii * H_ + h + 4];
      const float qv[8] = {qa.x, qa.y, qa.z, qa.w, qb.x, qb.y, qb.z, qb.w};
      float* acc = (ii == 0) ? &a0 : (ii == 1) ? &a1 : (ii == 2) ? &a2 : &a3;
      float s = *acc;
#pragma unroll
      for (int u = 0; u < 8; ++u) {
        const float p = qv[u] * kv[u];
        s = fmaf(ww[u], __builtin_amdgcn_rcpf(fmaf(p, p, 1.f)), s);
      }
      *acc = s;
    }
  }
  const size_t o = (size_t)(b * LQ_ + i0) * LK_ + j;
  if (j < vl) {
    sc[o]           = fmaf(-2.f, a0, Wsum);
    sc[o + LK_]     = fmaf(-2.f, a1, Wsum);
    sc[o + 2 * LK_] = fmaf(-2.f, a2, Wsum);
    sc[o + 3 * LK_] = fmaf(-2.f, a3, Wsum);
  }
}

// =====================================================================
// Kernel D: masked softmax + AV, TI=4 rows/block, 512 thr, AV unroll x8.
// sc is row-major [(b,i)][j] -> 4 coalesced loads.
// =====================================================================
__global__ __launch_bounds__(512) void softmax_av_kernel(
    const float* __restrict__ sc, const float* __restrict__ V,
    const int* __restrict__ valid_lens, float* __restrict__ out) {
  __shared__ float4 p4s[LK_];
  __shared__ float redm[8][4];
  __shared__ float reds[8][4];

  const int blk = blockIdx.x;
  const int b = blk >> 6;
  const int i0 = (blk & 63) * 4;
  const int vl = valid_lens[b];
  const int t = threadIdx.x;        // j
  const int lane = t & 63, wave = t >> 6;

  const float* __restrict__ srow = sc + (size_t)(b * LQ_ + i0) * LK_;
  const bool valid = t < vl;
  float s[4], m[4];
#pragma unroll
  for (int ii = 0; ii < 4; ++ii) {
    s[ii] = valid ? srow[ii * LK_ + t] : -3.0e38f;
    m[ii] = s[ii];
  }
#pragma unroll
  for (int off = 32; off; off >>= 1)
#pragma unroll
    for (int ii = 0; ii < 4; ++ii) m[ii] = fmaxf(m[ii], __shfl_xor(m[ii], off));
  if (lane == 0)
#pragma unroll
    for (int ii = 0; ii < 4; ++ii) redm[wave][ii] = m[ii];
  __syncthreads();
  float e[4], sum[4];
#pragma unroll
  for (int ii = 0; ii < 4; ++ii) {
    float mx = redm[0][ii];
#pragma unroll
    for (int w = 1; w < 8; ++w) mx = fmaxf(mx, redm[w][ii]);
    e[ii] = valid ? __expf(s[ii] - mx) : 0.f;
    sum[ii] = e[ii];
  }
#pragma unroll
  for (int off = 32; off; off >>= 1)
#pragma unroll
    for (int ii = 0; ii < 4; ++ii) sum[ii] += __shfl_xor(sum[ii], off);
  if (lane == 0)
#pragma unroll
    for (int ii = 0; ii < 4; ++ii) reds[wave][ii] = sum[ii];
  __syncthreads();
  {
    float4 pv;
    float tot[4];
#pragma unroll
    for (int ii = 0; ii < 4; ++ii) {
      tot[ii] = reds[0][ii];
#pragma unroll
      for (int w = 1; w < 8; ++w) tot[ii] += reds[w][ii];
    }
    pv.x = e[0] * __builtin_amdgcn_rcpf(tot[0]);
    pv.y = e[1] * __builtin_amdgcn_rcpf(tot[1]);
    pv.z = e[2] * __builtin_amdgcn_rcpf(tot[2]);
    pv.w = e[3] * __builtin_amdgcn_rcpf(tot[3]);
    p4s[t] = pv;
  }
  __syncthreads();

  const float* __restrict__ Vb = V + (size_t)b * LK_ * DV_ + t;
  float a[4] = {0.f, 0.f, 0.f, 0.f};
  int j = 0;
  const int jv = vl & ~7;
  for (; j < jv; j += 8) {
    float v[8];
#pragma unroll
    for (int u = 0; u < 8; ++u) v[u] = Vb[(size_t)(j + u) * DV_];
#pragma unroll
    for (int u = 0; u < 8; ++u) {
      const float4 pp = p4s[j + u];
      a[0] = fmaf(pp.x, v[u], a[0]); a[1] = fmaf(pp.y, v[u], a[1]);
      a[2] = fmaf(pp.z, v[u], a[2]); a[3] = fmaf(pp.w, v[u], a[3]);
    }
  }
  for (; j < vl; ++j) {
    const float v = Vb[(size_t)j * DV_];
    const float4 pp = p4s[j];
    a[0] = fmaf(pp.x, v, a[0]); a[1] = fmaf(pp.y, v, a[1]);
    a[2] = fmaf(pp.z, v, a[2]); a[3] = fmaf(pp.w, v, a[3]);
  }
#pragma unroll
  for (int ii = 0; ii < 4; ++ii)
    out[(size_t)(b * LQ_ + i0 + ii) * DV_ + t] = a[ii];
}

extern "C" void kernel_launch(void* const* d_in, const int* in_sizes, int n_in,
                              void* d_out, int out_size, void* d_ws, size_t ws_size,
                              hipStream_t stream) {
  const float* queries    = (const float*)d_in[0];
  const float* keys       = (const float*)d_in[1];
  const float* values     = (const float*)d_in[2];
  const int*   valid_lens = (const int*)d_in[3];
  const float* Wq         = (const float*)d_in[4];
  const float* Wk         = (const float*)d_in[5];
  const float* wv         = (const float*)d_in[6];
  float* out = (float*)d_out;

  char* ws = (char*)d_ws;
  float* qpart   = (float*)ws;                           // 4 x 1 MB  @ 0
  float* ekTpart = (float*)(ws + (size_t)( 4 << 20));    // 4 x 2 MB  @ 4 MB
  float* eq      = (float*)(ws + (size_t)(12 << 20));    // 1 MB      @ 12 MB
  float* ekT     = (float*)(ws + (size_t)(13 << 20));    // 2 MB      @ 13 MB
  float* sc      = (float*)(ws + (size_t)(15 << 20));    // 2 MB      @ 15 MB
  float* wsum    = (float*)(ws + (size_t)(17 << 20));    // 4 B       @ 17 MB

  proj_partial_kernel<<<384, 256, 0, stream>>>(
      queries, keys, Wq, Wk, valid_lens, qpart, ekTpart);
  combine_exp_kernel<<<384, 512, 0, stream>>>(
      qpart, ekTpart, wv, eq, ekT, wsum);
  scores_kernel<<<512, 256, 0, stream>>>(
      eq, ekT, wv, wsum, valid_lens, sc);
  softmax_av_kernel<<<B_ * (LQ_ / 4), 512, 0, stream>>>(
      sc, values, valid_lens, out);
}

// Round 11
// 62.723 us; speedup vs baseline: 1.0174x; 1.0174x over previous
//
#include <hip/hip_runtime.h>

#define B_   4
#define LQ_  256
#define LK_  512
#define DIN_ 512
#define H_   256
#define DV_  512

#define L2E 1.4426950408889634f   // log2(e)
// tanh(x) = 1 - 2/(e^{2x}+1);  e^{2(q+k)} = (e^q * e^k)^2.
// combine stores eq = 2^clamp(qp*L2E,±126) (finite, nonzero -> no NaN;
// p*p overflow -> inf -> rcp=0 -> exact tanh saturation).

// =====================================================================
// Kernel A: proj PARTIAL GEMM. tile 64 rows x 128 h x 128 d (d-split 4).
// 256 thr: hthr=t&31 (h=4*hthr), rthr=t>>5 (rows rthr*8..+7). micro 8rx4h.
// BOTH outputs row-major [ds][(b,row)][h].
// grid = Q:128 + K:256 -> 384 blocks (~272 live; dead K tiles exit).
// =====================================================================
__global__ __launch_bounds__(256) void proj_partial_kernel(
    const float* __restrict__ Q, const float* __restrict__ K,
    const float* __restrict__ Wq, const float* __restrict__ Wk,
    const int* __restrict__ valid_lens,
    float* __restrict__ qpart, float* __restrict__ ekpart) {
  __shared__ float xs[64][68];
  __shared__ float ws[64][132];

  const int blk = blockIdx.x;
  const bool isQ = blk < 128;
  int b, row0, h0, ds;
  if (isQ) {
    const int qi = blk;
    ds = qi & 3; h0 = ((qi >> 2) & 1) * 128;
    const int rt = qi >> 3;            // 0..15
    b = rt >> 2; row0 = (rt & 3) * 64;
  } else {
    const int u = blk - 128;
    ds = u & 3; h0 = ((u >> 2) & 1) * 128;
    const int rt = u >> 3;             // 0..31, batch-interleaved
    b = rt & 3; row0 = (rt >> 2) * 64;
    if (row0 >= valid_lens[b]) return; // dead K tile (uniform, before barriers)
  }
  const int L = isQ ? LQ_ : LK_;
  const float* __restrict__ X = (isQ ? Q : K) + ((size_t)(b * L + row0)) * DIN_ + ds * 128;
  const float* __restrict__ Wb = (isQ ? Wq : Wk) + (size_t)(ds * 128) * H_ + h0;

  const int t = threadIdx.x;
  const int hthr = t & 31;    // h = h0 + 4*hthr
  const int rthr = t >> 5;    // rows row0 + rthr*8 .. +7

  float acc[8][4];
#pragma unroll
  for (int r = 0; r < 8; ++r)
#pragma unroll
    for (int c = 0; c < 4; ++c) acc[r][c] = 0.f;

  for (int dd = 0; dd < 128; dd += 64) {
    __syncthreads();
#pragma unroll
    for (int u = 0; u < 4; ++u) {
      const int f = t + 256 * u;
      const int r = f >> 4, c4 = (f & 15) << 2;
      *(float4*)&xs[r][c4] = *(const float4*)&X[(size_t)r * DIN_ + dd + c4];
    }
#pragma unroll
    for (int u = 0; u < 8; ++u) {
      const int f = t + 256 * u;
      const int k = f >> 5, c4 = (f & 31) << 2;
      *(float4*)&ws[k][c4] = *(const float4*)&Wb[(size_t)(dd + k) * H_ + c4];
    }
    __syncthreads();

    for (int k = 0; k < 64; k += 8) {
      float4 w4[8];
#pragma unroll
      for (int k8 = 0; k8 < 8; ++k8)
        w4[k8] = *(const float4*)&ws[k + k8][4 * hthr];
#pragma unroll
      for (int rr = 0; rr < 8; ++rr) {
        const float4 xa = *(const float4*)&xs[rthr * 8 + rr][k];
        const float4 xb = *(const float4*)&xs[rthr * 8 + rr][k + 4];
        const float xv[8] = {xa.x, xa.y, xa.z, xa.w, xb.x, xb.y, xb.z, xb.w};
#pragma unroll
        for (int k8 = 0; k8 < 8; ++k8) {
          acc[rr][0] = fmaf(xv[k8], w4[k8].x, acc[rr][0]);
          acc[rr][1] = fmaf(xv[k8], w4[k8].y, acc[rr][1]);
          acc[rr][2] = fmaf(xv[k8], w4[k8].z, acc[rr][2]);
          acc[rr][3] = fmaf(xv[k8], w4[k8].w, acc[rr][3]);
        }
      }
    }
  }

  float* dst = isQ ? (qpart + (size_t)ds * (B_ * LQ_ * H_))
                   : (ekpart + (size_t)ds * (B_ * LK_ * H_));
#pragma unroll
  for (int rr = 0; rr < 8; ++rr) {
    const int row = row0 + rthr * 8 + rr;
    float4 o = {acc[rr][0], acc[rr][1], acc[rr][2], acc[rr][3]};
    *(float4*)&dst[(size_t)(b * L + row) * H_ + h0 + 4 * hthr] = o;
  }
}

// =====================================================================
// Kernel B: combine 4 d-partials + exp convert (pure elementwise float4).
// eq[(b,i)][h], ek[(b,j)][h] both row-major. Block 0 computes wsum.
// =====================================================================
__global__ __launch_bounds__(512) void combine_exp_kernel(
    const float* __restrict__ qpart, const float* __restrict__ ekpart,
    const float* __restrict__ wv,
    float* __restrict__ eq, float* __restrict__ ek, float* __restrict__ wsum) {
  const int idx = blockIdx.x * 512 + threadIdx.x;
  const int NQ4 = B_ * LQ_ * H_ / 4;     // 65536
  const float4* src;
  float4* dst;
  size_t stride4;
  int k4;
  if (idx < NQ4) {
    src = (const float4*)qpart; dst = (float4*)eq;
    stride4 = NQ4; k4 = idx;
  } else {
    src = (const float4*)ekpart; dst = (float4*)ek;
    stride4 = B_ * LK_ * H_ / 4; k4 = idx - NQ4;
  }
  float4 a = src[k4];
  float4 b1 = src[stride4 + k4];
  float4 c = src[2 * stride4 + k4];
  float4 d = src[3 * stride4 + k4];
  float4 o;
  o.x = exp2f(fminf(fmaxf((a.x + b1.x + c.x + d.x) * L2E, -126.f), 126.f));
  o.y = exp2f(fminf(fmaxf((a.y + b1.y + c.y + d.y) * L2E, -126.f), 126.f));
  o.z = exp2f(fminf(fmaxf((a.z + b1.z + c.z + d.z) * L2E, -126.f), 126.f));
  o.w = exp2f(fminf(fmaxf((a.w + b1.w + c.w + d.w) * L2E, -126.f), 126.f));
  dst[k4] = o;

  if (blockIdx.x == 0 && threadIdx.x < 64) {
    const int t = threadIdx.x;
    float s = wv[t] + wv[t + 64] + wv[t + 128] + wv[t + 192];
#pragma unroll
    for (int off = 32; off; off >>= 1) s += __shfl_xor(s, off);
    if (t == 0) *wsum = s;
  }
}

// =====================================================================
// Kernel C: LDS-tiled scores. Block = (b, 32 i, 32 j); both operand tiles
// staged in LDS (x32 reuse, ~16 MB total global traffic). Thread 2i x 2j.
//   sc[(b,i)][j] = Wsum - 2*sum_h wv[h]*rcp((eq*ek)^2+1)
// eq_s padded to 260 (rows 2ty -> 4 distinct banks, conflict-free b128);
// ek_s transposed [h][36] (lanes read consecutive j -> conflict-free).
// grid = B*(LQ/32)*(LK/32) = 512, jt-outer; dead j-tiles exit.
// =====================================================================
__global__ __launch_bounds__(256) void scores_kernel(
    const float* __restrict__ eq, const float* __restrict__ ek,
    const float* __restrict__ wv, const float* __restrict__ wsum,
    const int* __restrict__ valid_lens, float* __restrict__ sc) {
  __shared__ float eq_s[32][260];   // 33.3 KB
  __shared__ float ek_s[256][36];   // 36.9 KB
  __shared__ float wv_s[260];

  const int blk = blockIdx.x;
  const int b  = blk & 3;
  const int it = (blk >> 2) & 7;
  const int jt = blk >> 5;
  const int vl = valid_lens[b];
  if (jt * 32 >= vl) return;
  const int t = threadIdx.x;
  const int tx = t & 15, ty = t >> 4;
  const int i0 = it * 32, j0 = jt * 32;

  // stage eq rows i0..i0+31 (coalesced float4)
  const float* __restrict__ eqb = eq + ((size_t)(b * LQ_ + i0)) * H_;
#pragma unroll
  for (int u = 0; u < 8; ++u) {
    const int f = t + 256 * u;          // 0..2047
    const int r = f >> 6, c4 = (f & 63) << 2;
    *(float4*)&eq_s[r][c4] = *(const float4*)&eqb[(size_t)r * H_ + c4];
  }
  // stage ek rows j0..j0+31, transposed into ek_s[h][j]
  const float* __restrict__ ekb = ek + ((size_t)(b * LK_ + j0)) * H_;
  {
    const int hq = t & 63, jg = t >> 6;
#pragma unroll
    for (int p = 0; p < 8; ++p) {
      const int jj = jg + 4 * p;
      const float4 v = *(const float4*)&ekb[(size_t)jj * H_ + 4 * hq];
      ek_s[4 * hq][jj]     = v.x;
      ek_s[4 * hq + 1][jj] = v.y;
      ek_s[4 * hq + 2][jj] = v.z;
      ek_s[4 * hq + 3][jj] = v.w;
    }
  }
  if (t < 64) {
#pragma unroll
    for (int u = 0; u < 4; ++u) wv_s[t + 64 * u] = wv[t + 64 * u];
  }
  __syncthreads();

  const float Wsum = *wsum;
  float a00 = 0.f, a01 = 0.f, a10 = 0.f, a11 = 0.f;
#pragma unroll 2
  for (int hq = 0; hq < 64; ++hq) {
    const float4 q0 = *(const float4*)&eq_s[2 * ty][4 * hq];
    const float4 q1 = *(const float4*)&eq_s[2 * ty + 1][4 * hq];
    const float4 w4 = *(const float4*)&wv_s[4 * hq];
    const float qa[4] = {q0.x, q0.y, q0.z, q0.w};
    const float qb[4] = {q1.x, q1.y, q1.z, q1.w};
    const float ww[4] = {w4.x, w4.y, w4.z, w4.w};
#pragma unroll
    for (int u = 0; u < 4; ++u) {
      const float2 kk = *(const float2*)&ek_s[4 * hq + u][2 * tx];
      float p;
      p = qa[u] * kk.x; a00 = fmaf(ww[u], __builtin_amdgcn_rcpf(fmaf(p, p, 1.f)), a00);
      p = qa[u] * kk.y; a01 = fmaf(ww[u], __builtin_amdgcn_rcpf(fmaf(p, p, 1.f)), a01);
      p = qb[u] * kk.x; a10 = fmaf(ww[u], __builtin_amdgcn_rcpf(fmaf(p, p, 1.f)), a10);
      p = qb[u] * kk.y; a11 = fmaf(ww[u], __builtin_amdgcn_rcpf(fmaf(p, p, 1.f)), a11);
    }
  }
  const int i = i0 + 2 * ty, j = j0 + 2 * tx;
  float2 r0 = {fmaf(-2.f, a00, Wsum), fmaf(-2.f, a01, Wsum)};
  float2 r1 = {fmaf(-2.f, a10, Wsum), fmaf(-2.f, a11, Wsum)};
  *(float2*)&sc[(size_t)(b * LQ_ + i) * LK_ + j] = r0;
  *(float2*)&sc[(size_t)(b * LQ_ + i + 1) * LK_ + j] = r1;
}

// =====================================================================
// Kernel D: masked softmax + AV, TI=4 rows/block, 512 thr, AV unroll x8.
// =====================================================================
__global__ __launch_bounds__(512) void softmax_av_kernel(
    const float* __restrict__ sc, const float* __restrict__ V,
    const int* __restrict__ valid_lens, float* __restrict__ out) {
  __shared__ float4 p4s[LK_];
  __shared__ float redm[8][4];
  __shared__ float reds[8][4];

  const int blk = blockIdx.x;
  const int b = blk >> 6;
  const int i0 = (blk & 63) * 4;
  const int vl = valid_lens[b];
  const int t = threadIdx.x;        // j
  const int lane = t & 63, wave = t >> 6;

  const float* __restrict__ srow = sc + (size_t)(b * LQ_ + i0) * LK_;
  const bool valid = t < vl;
  float s[4], m[4];
#pragma unroll
  for (int ii = 0; ii < 4; ++ii) {
    s[ii] = valid ? srow[ii * LK_ + t] : -3.0e38f;
    m[ii] = s[ii];
  }
#pragma unroll
  for (int off = 32; off; off >>= 1)
#pragma unroll
    for (int ii = 0; ii < 4; ++ii) m[ii] = fmaxf(m[ii], __shfl_xor(m[ii], off));
  if (lane == 0)
#pragma unroll
    for (int ii = 0; ii < 4; ++ii) redm[wave][ii] = m[ii];
  __syncthreads();
  float e[4], sum[4];
#pragma unroll
  for (int ii = 0; ii < 4; ++ii) {
    float mx = redm[0][ii];
#pragma unroll
    for (int w = 1; w < 8; ++w) mx = fmaxf(mx, redm[w][ii]);
    e[ii] = valid ? __expf(s[ii] - mx) : 0.f;
    sum[ii] = e[ii];
  }
#pragma unroll
  for (int off = 32; off; off >>= 1)
#pragma unroll
    for (int ii = 0; ii < 4; ++ii) sum[ii] += __shfl_xor(sum[ii], off);
  if (lane == 0)
#pragma unroll
    for (int ii = 0; ii < 4; ++ii) reds[wave][ii] = sum[ii];
  __syncthreads();
  {
    float4 pv;
    float tot[4];
#pragma unroll
    for (int ii = 0; ii < 4; ++ii) {
      tot[ii] = reds[0][ii];
#pragma unroll
      for (int w = 1; w < 8; ++w) tot[ii] += reds[w][ii];
    }
    pv.x = e[0] * __builtin_amdgcn_rcpf(tot[0]);
    pv.y = e[1] * __builtin_amdgcn_rcpf(tot[1]);
    pv.z = e[2] * __builtin_amdgcn_rcpf(tot[2]);
    pv.w = e[3] * __builtin_amdgcn_rcpf(tot[3]);
    p4s[t] = pv;
  }
  __syncthreads();

  const float* __restrict__ Vb = V + (size_t)b * LK_ * DV_ + t;
  float a[4] = {0.f, 0.f, 0.f, 0.f};
  int j = 0;
  const int jv = vl & ~7;
  for (; j < jv; j += 8) {
    float v[8];
#pragma unroll
    for (int u = 0; u < 8; ++u) v[u] = Vb[(size_t)(j + u) * DV_];
#pragma unroll
    for (int u = 0; u < 8; ++u) {
      const float4 pp = p4s[j + u];
      a[0] = fmaf(pp.x, v[u], a[0]); a[1] = fmaf(pp.y, v[u], a[1]);
      a[2] = fmaf(pp.z, v[u], a[2]); a[3] = fmaf(pp.w, v[u], a[3]);
    }
  }
  for (; j < vl; ++j) {
    const float v = Vb[(size_t)j * DV_];
    const float4 pp = p4s[j];
    a[0] = fmaf(pp.x, v, a[0]); a[1] = fmaf(pp.y, v, a[1]);
    a[2] = fmaf(pp.z, v, a[2]); a[3] = fmaf(pp.w, v, a[3]);
  }
#pragma unroll
  for (int ii = 0; ii < 4; ++ii)
    out[(size_t)(b * LQ_ + i0 + ii) * DV_ + t] = a[ii];
}

extern "C" void kernel_launch(void* const* d_in, const int* in_sizes, int n_in,
                              void* d_out, int out_size, void* d_ws, size_t ws_size,
                              hipStream_t stream) {
  const float* queries    = (const float*)d_in[0];
  const float* keys       = (const float*)d_in[1];
  const float* values     = (const float*)d_in[2];
  const int*   valid_lens = (const int*)d_in[3];
  const float* Wq         = (const float*)d_in[4];
  const float* Wk         = (const float*)d_in[5];
  const float* wv         = (const float*)d_in[6];
  float* out = (float*)d_out;

  char* ws = (char*)d_ws;
  float* qpart  = (float*)ws;                           // 4 x 1 MB  @ 0
  float* ekpart = (float*)(ws + (size_t)( 4 << 20));    // 4 x 2 MB  @ 4 MB
  float* eq     = (float*)(ws + (size_t)(12 << 20));    // 1 MB      @ 12 MB
  float* ek     = (float*)(ws + (size_t)(13 << 20));    // 2 MB      @ 13 MB
  float* sc     = (float*)(ws + (size_t)(15 << 20));    // 2 MB      @ 15 MB
  float* wsum   = (float*)(ws + (size_t)(17 << 20));    // 4 B       @ 17 MB

  proj_partial_kernel<<<384, 256, 0, stream>>>(
      queries, keys, Wq, Wk, valid_lens, qpart, ekpart);
  combine_exp_kernel<<<384, 512, 0, stream>>>(
      qpart, ekpart, wv, eq, ek, wsum);
  scores_kernel<<<512, 256, 0, stream>>>(
      eq, ek, wv, wsum, valid_lens, sc);
  softmax_av_kernel<<<B_ * (LQ_ / 4), 512, 0, stream>>>(
      sc, values, valid_lens, out);
}